// Round 10
// baseline (440.554 us; speedup 1.0000x reference)
//
#include <hip/hip_runtime.h>
#include <hip/hip_fp16.h>

#define NFEAT_IN 21
#define NHID 16
#define NOUT 6
#define BSHIFT 9
#define BW (1 << BSHIFT)     // 512 nodes per bucket
#define NB 512               // bucket array size (supports n <= 262144)
#define PB 256
#define EPT 32
#define CHUNK (PB * EPT)     // 8192 edges per partition block

typedef unsigned int u32x4 __attribute__((ext_vector_type(4)));

// static arenas: bucket b's region starts at b*cap
__global__ void k_init_bcur(int* __restrict__ bcur, int cap) {
    int b = blockIdx.x * blockDim.x + threadIdx.x;
    if (b < NB) bcur[b] = b * cap;
}

// LDS-local bucket sort per 8192-edge chunk, then COALESCED emission.
__global__ __launch_bounds__(256) void
k_partition(const int* __restrict__ src, const int* __restrict__ dst,
            int* __restrict__ bcur, unsigned int* __restrict__ bucketed,
            int cap, int ne) {
    __shared__ unsigned int ebd[CHUNK];     // dst value (0xFFFFFFFF = invalid)
    __shared__ unsigned short sidx[CHUNK];  // bucket-sorted pos -> chunk idx
    __shared__ int lcnt[NB], lstart[NB], lcur[NB], lbase[NB];
    __shared__ int s[PB];
    __shared__ int sh_total;
    int t = threadIdx.x;
    long base = (long)blockIdx.x * CHUNK;
    for (int b = t; b < NB; b += PB) lcnt[b] = 0;
    __syncthreads();
#pragma unroll
    for (int k = 0; k < EPT; k++) {
        int idx = t + k * PB;
        long e = base + idx;
        unsigned int v = 0xFFFFFFFFu;
        if (e < ne) {
            int d = dst[e];
            v = (unsigned int)d;
            atomicAdd(&lcnt[d >> BSHIFT], 1);
        }
        ebd[idx] = v;
    }
    __syncthreads();
    int v0 = lcnt[2 * t], v1 = lcnt[2 * t + 1];
    int pair = v0 + v1;
    s[t] = pair;
    __syncthreads();
    for (int off = 1; off < PB; off <<= 1) {
        int tv = (t >= off) ? s[t - off] : 0;
        __syncthreads();
        s[t] += tv;
        __syncthreads();
    }
    int ex = s[t] - pair;
    lstart[2 * t] = ex;          lcur[2 * t] = ex;
    lstart[2 * t + 1] = ex + v0; lcur[2 * t + 1] = ex + v0;
    if (v0 > 0) lbase[2 * t]     = atomicAdd(&bcur[2 * t],     v0);
    if (v1 > 0) lbase[2 * t + 1] = atomicAdd(&bcur[2 * t + 1], v1);
    if (t == PB - 1) sh_total = s[PB - 1];
    __syncthreads();
#pragma unroll
    for (int k = 0; k < EPT; k++) {
        int idx = t + k * PB;
        unsigned int d = ebd[idx];
        if (d != 0xFFFFFFFFu) {
            int r = atomicAdd(&lcur[d >> BSHIFT], 1);
            sidx[r] = (unsigned short)idx;
        }
    }
    __syncthreads();
    int total = sh_total;
#pragma unroll
    for (int k = 0; k < EPT; k++) {
        int j = t + k * PB;
        if (j < total) {
            int idx = sidx[j];
            unsigned int d = ebd[idx];
            int b = d >> BSHIFT;
            long gpos = (long)lbase[b] + (j - lstart[b]);
            int s_ = src[base + idx];
            if (gpos < (long)(b + 1) * cap)   // arena overflow guard (~12 sigma)
                bucketed[gpos] = ((unsigned int)s_ << BSHIFT) | (d & (BW - 1));
        }
    }
}

// counts + exclusive scan over <=512 buckets (1 block, 512 threads)
__global__ __launch_bounds__(512) void
k_cnt_scan(const int* __restrict__ bcur, int cap, int* __restrict__ cnt,
           int* __restrict__ csr_boff, int nb) {
    __shared__ int s[512];
    int t = threadIdx.x;
    int c = (t < nb) ? (bcur[t] - t * cap) : 0;
    s[t] = c;
    __syncthreads();
    for (int off = 1; off < 512; off <<= 1) {
        int tv = (t >= off) ? s[t - off] : 0;
        __syncthreads();
        s[t] += tv;
        __syncthreads();
    }
    if (t < nb) { cnt[t] = c; csr_boff[t] = s[t] - c; }
}

// Counting-sort each bucket by dst_local -> exact dst-sorted CSR.
__global__ __launch_bounds__(512) void
k_sort(const unsigned int* __restrict__ bucketed, int cap,
       const int* __restrict__ cnt, const int* __restrict__ csr_boff,
       int* __restrict__ csr_src, int* __restrict__ node_off,
       float* __restrict__ dinv, int n, int ne, int nb) {
    __shared__ int bin[BW], sc[BW], bcur_l[BW];
    int b = blockIdx.x, t = threadIdx.x;
    bin[t] = 0;
    __syncthreads();
    size_t s0r = (size_t)b * cap;
    int c = cnt[b], s0c = csr_boff[b];
    for (int j = t; j < c; j += 512) atomicAdd(&bin[bucketed[s0r + j] & (BW - 1)], 1);
    __syncthreads();
    sc[t] = bin[t];
    __syncthreads();
    for (int off = 1; off < BW; off <<= 1) {
        int v = (t >= off) ? sc[t - off] : 0;
        __syncthreads();
        sc[t] += v;
        __syncthreads();
    }
    {
        int ex = sc[t] - bin[t];            // exclusive prefix
        bcur_l[t] = s0c + ex;
        node_off[(b << BSHIFT) + t] = s0c + ex;
        int node = (b << BSHIFT) + t;
        if (node < n) dinv[node] = rsqrtf((float)bin[t] + 1.0f);
    }
    if (b == 0 && t == 0) node_off[(size_t)nb << BSHIFT] = ne;  // sentinel
    __syncthreads();
    for (int j = t; j < c; j += 512) {
        unsigned int e = bucketed[s0r + j];
        int pos = atomicAdd(&bcur_l[e & (BW - 1)], 1);
        csr_src[pos] = (int)(e >> BSHIFT);
    }
}

// Round-9 finding: in-kernel phase split fails from inter-block phase drift
// (FETCH 310->295MB only). Fix needs kernel-boundary alignment: hs1 is split
// into two 16B/row tables (3.2MB each < 4MB per-XCD L2), and k_agg1 becomes
// two launches, each sweeping all edges against ONE L2-resident table.
// k_dense1 writes lo (features 0-7) and hi (8-15) tables.
__global__ void k_dense1(const float* __restrict__ x, const float* __restrict__ W1,
                         const float* __restrict__ dinv,
                         __half2* __restrict__ hs1lo, __half2* __restrict__ hs1hi,
                         int n) {
    __shared__ float sW[NFEAT_IN * NHID];
    for (int t = threadIdx.x; t < NFEAT_IN * NHID; t += blockDim.x) sW[t] = W1[t];
    __syncthreads();
    int i = blockIdx.x * blockDim.x + threadIdx.x;
    if (i >= n) return;
    float xi[NFEAT_IN];
#pragma unroll
    for (int k = 0; k < NFEAT_IN; k++) xi[k] = x[(size_t)i * NFEAT_IN + k];
    float di = dinv[i];
    float r[NHID];
#pragma unroll
    for (int j = 0; j < NHID; j++) {
        float acc = 0.f;
#pragma unroll
        for (int k = 0; k < NFEAT_IN; k++) acc += xi[k] * sW[k * NHID + j];
        r[j] = acc * di;
    }
    __half2* lp = hs1lo + (size_t)i * 4;
    __half2* hp = hs1hi + (size_t)i * 4;
#pragma unroll
    for (int q = 0; q < 4; q++) {
        lp[q] = __floats2half2_rn(r[2 * q], r[2 * q + 1]);
        hp[q] = __floats2half2_rn(r[8 + 2 * q], r[8 + 2 * q + 1]);
    }
}

__device__ __forceinline__ void addh8(float* acc, u32x4 u) {
    unsigned int us[4] = {u[0], u[1], u[2], u[3]};
#pragma unroll
    for (int q = 0; q < 4; q++) {
        float2 f = __half22float2(*(const __half2*)&us[q]);
        acc[2 * q] += f.x;
        acc[2 * q + 1] += f.y;
    }
}

// Sweep 1: gather lo-halves (3.2MB table, L2-resident), spill 8-float partial.
// csr reads nontemporal to keep the table hot under LRU.
__global__ __launch_bounds__(256) void
k_agg1a(const int* __restrict__ csr_src, const int* __restrict__ node_off,
        const u32x4* __restrict__ hlo, float* __restrict__ pacc, int n) {
    int i = blockIdx.x * blockDim.x + threadIdx.x;
    if (i >= n) return;
    int beg = node_off[i], end = node_off[i + 1];
    float acc[8];
    {   // self (A+I)
        u32x4 u = hlo[i];
        unsigned int us[4] = {u[0], u[1], u[2], u[3]};
#pragma unroll
        for (int q = 0; q < 4; q++) {
            float2 f = __half22float2(*(const __half2*)&us[q]);
            acc[2 * q] = f.x;
            acc[2 * q + 1] = f.y;
        }
    }
    int j = beg;
    for (; j + 8 <= end; j += 8) {
        int sid[8];
#pragma unroll
        for (int q = 0; q < 8; q++) sid[q] = __builtin_nontemporal_load(csr_src + j + q);
        u32x4 u[8];
#pragma unroll
        for (int q = 0; q < 8; q++) u[q] = hlo[(size_t)sid[q]];
#pragma unroll
        for (int q = 0; q < 8; q++) addh8(acc, u[q]);
    }
    for (; j < end; j++) addh8(acc, hlo[(size_t)csr_src[j]]);
    float4* pp = (float4*)(pacc + (size_t)i * 8);
    pp[0] = make_float4(acc[0], acc[1], acc[2], acc[3]);
    pp[1] = make_float4(acc[4], acc[5], acc[6], acc[7]);
}

// Sweep 2: gather hi-halves, merge lo partial, relu + dense2 + write hs2h.
__global__ __launch_bounds__(256) void
k_agg1b(const int* __restrict__ csr_src, const int* __restrict__ node_off,
        const u32x4* __restrict__ hhi, const float* __restrict__ pacc,
        const float* __restrict__ b1, const float* __restrict__ W2,
        const float* __restrict__ dinv, __half2* __restrict__ hs2h, int n) {
    __shared__ float sW[NHID * NOUT];
    __shared__ float sb[NHID];
    int t = threadIdx.x;
    if (t < NHID * NOUT) sW[t] = W2[t];
    if (t < NHID) sb[t] = b1[t];
    __syncthreads();
    int i = blockIdx.x * blockDim.x + t;
    if (i >= n) return;
    int beg = node_off[i], end = node_off[i + 1];
    float acc[8];
    {   // self (A+I)
        u32x4 u = hhi[i];
        unsigned int us[4] = {u[0], u[1], u[2], u[3]};
#pragma unroll
        for (int q = 0; q < 4; q++) {
            float2 f = __half22float2(*(const __half2*)&us[q]);
            acc[2 * q] = f.x;
            acc[2 * q + 1] = f.y;
        }
    }
    int j = beg;
    for (; j + 8 <= end; j += 8) {
        int sid[8];
#pragma unroll
        for (int q = 0; q < 8; q++) sid[q] = __builtin_nontemporal_load(csr_src + j + q);
        u32x4 u[8];
#pragma unroll
        for (int q = 0; q < 8; q++) u[q] = hhi[(size_t)sid[q]];
#pragma unroll
        for (int q = 0; q < 8; q++) addh8(acc, u[q]);
    }
    for (; j < end; j++) addh8(acc, hhi[(size_t)csr_src[j]]);
    const float4* pp = (const float4*)(pacc + (size_t)i * 8);
    float4 p0 = pp[0], p1 = pp[1];
    float di = dinv[i];
    float z[NHID];
    z[0] = fmaxf(p0.x * di + sb[0], 0.0f);
    z[1] = fmaxf(p0.y * di + sb[1], 0.0f);
    z[2] = fmaxf(p0.z * di + sb[2], 0.0f);
    z[3] = fmaxf(p0.w * di + sb[3], 0.0f);
    z[4] = fmaxf(p1.x * di + sb[4], 0.0f);
    z[5] = fmaxf(p1.y * di + sb[5], 0.0f);
    z[6] = fmaxf(p1.z * di + sb[6], 0.0f);
    z[7] = fmaxf(p1.w * di + sb[7], 0.0f);
#pragma unroll
    for (int k = 0; k < 8; k++) z[8 + k] = fmaxf(acc[k] * di + sb[8 + k], 0.0f);
    float h[8];
#pragma unroll
    for (int kk = 0; kk < NOUT; kk++) {
        float s = 0.f;
#pragma unroll
        for (int jj = 0; jj < NHID; jj++) s += z[jj] * sW[jj * NOUT + kk];
        h[kk] = s * di;
    }
    h[6] = 0.f; h[7] = 0.f;
    __half2* op = hs2h + (size_t)i * 4;
#pragma unroll
    for (int q = 0; q < 4; q++) op[q] = __floats2half2_rn(h[2 * q], h[2 * q + 1]);
}

// CSR aggregate layer2 + bias + log_softmax. One thread per dst node.
// (hs2h table = 3.2MB — fits per-XCD L2 as-is.)
__global__ __launch_bounds__(256) void
k_agg2(const int* __restrict__ csr_src, const int* __restrict__ node_off,
       const __half2* __restrict__ hs2h, const float* __restrict__ b2,
       const float* __restrict__ dinv, float* __restrict__ out, int n) {
    __shared__ float sb[NOUT];
    int t = threadIdx.x;
    if (t < NOUT) sb[t] = b2[t];
    __syncthreads();
    int i = blockIdx.x * blockDim.x + t;
    if (i >= n) return;
    int beg = node_off[i], end = node_off[i + 1];
    const u32x4* hb = (const u32x4*)hs2h;
    float acc[NOUT];
    {   // self
        u32x4 u = hb[(size_t)i];
        unsigned int us[3] = {u[0], u[1], u[2]};
#pragma unroll
        for (int q = 0; q < 3; q++) {
            float2 f = __half22float2(*(const __half2*)&us[q]);
            acc[2 * q] = f.x;
            acc[2 * q + 1] = f.y;
        }
    }
    int j = beg;
    for (; j + 8 <= end; j += 8) {
        int sid[8];
#pragma unroll
        for (int q = 0; q < 8; q++) sid[q] = __builtin_nontemporal_load(csr_src + j + q);
        u32x4 u[8];
#pragma unroll
        for (int q = 0; q < 8; q++) u[q] = hb[(size_t)sid[q]];
#pragma unroll
        for (int q = 0; q < 8; q++) {
            unsigned int us[3] = {u[q][0], u[q][1], u[q][2]};
#pragma unroll
            for (int w = 0; w < 3; w++) {
                float2 fv = __half22float2(*(const __half2*)&us[w]);
                acc[2 * w] += fv.x;
                acc[2 * w + 1] += fv.y;
            }
        }
    }
    for (; j < end; j++) {
        u32x4 u = hb[(size_t)csr_src[j]];
        unsigned int us[3] = {u[0], u[1], u[2]};
#pragma unroll
        for (int w = 0; w < 3; w++) {
            float2 fv = __half22float2(*(const __half2*)&us[w]);
            acc[2 * w] += fv.x;
            acc[2 * w + 1] += fv.y;
        }
    }
    float di = dinv[i];
    float v[NOUT];
#pragma unroll
    for (int k = 0; k < NOUT; k++) v[k] = acc[k] * di + sb[k];
    float m = -1e30f;
#pragma unroll
    for (int k = 0; k < NOUT; k++) m = fmaxf(m, v[k]);
    float se = 0.f;
#pragma unroll
    for (int k = 0; k < NOUT; k++) se += expf(v[k] - m);
    float l = logf(se);
#pragma unroll
    for (int k = 0; k < NOUT; k++) out[(size_t)i * NOUT + k] = v[k] - m - l;
}

extern "C" void kernel_launch(void* const* d_in, const int* in_sizes, int n_in,
                              void* d_out, int out_size, void* d_ws, size_t ws_size,
                              hipStream_t stream) {
    const float* x  = (const float*)d_in[0];
    const int*   ei = (const int*)d_in[1];
    const float* W1 = (const float*)d_in[2];
    const float* b1 = (const float*)d_in[3];
    const float* W2 = (const float*)d_in[4];
    const float* b2 = (const float*)d_in[5];
    float* out = (float*)d_out;

    int n  = in_sizes[0] / NFEAT_IN;   // 200000
    int ne = in_sizes[1] / 2;          // 6400000
    const int* src = ei;
    const int* dst = ei + ne;

    int nb = (n + BW - 1) >> BSHIFT;          // 391
    // arena capacity per bucket: mean + ~12 sigma headroom for uniform dst
    int cap = (ne + nb - 1) / nb + ne / (nb * 16) + 1536;

    char* base = (char*)d_ws;
    size_t off = 0;
    auto alloc = [&](size_t bytes) {
        void* p = base + off;
        off += (bytes + 63) & ~(size_t)63;
        return p;
    };
    int* bcur     = (int*)alloc(NB * 4);
    int* cnt      = (int*)alloc(NB * 4);
    int* csr_boff = (int*)alloc(NB * 4);
    unsigned int* bucketed = (unsigned int*)alloc((size_t)nb * cap * 4);
    int* csr_src  = (int*)alloc((size_t)ne * 4);
    int* node_off = (int*)alloc(((size_t)nb * BW + 1) * 4);
    float* dinv   = (float*)alloc((size_t)n * 4);
    // hs1lo/hs1hi/hs2h/pacc overlay the arena (dead after k_sort):
    // need n*(16+16+16+32) = n*80 bytes.
    __half2 *hs1lo, *hs1hi, *hs2h;
    float* pacc;
    if ((size_t)nb * cap * 4 >= (size_t)n * 80) {
        hs1lo = (__half2*)bucketed;
        hs1hi = (__half2*)((char*)bucketed + (size_t)n * 16);
        hs2h  = (__half2*)((char*)bucketed + (size_t)n * 32);
        pacc  = (float*)((char*)bucketed + (size_t)n * 48);
    } else {
        hs1lo = (__half2*)alloc((size_t)n * 16);
        hs1hi = (__half2*)alloc((size_t)n * 16);
        hs2h  = (__half2*)alloc((size_t)n * 16);
        pacc  = (float*)alloc((size_t)n * 32);
    }

    int gp = (ne + CHUNK - 1) / CHUNK;        // 782
    int gn = (n + 255) / 256;

    k_init_bcur<<<(NB + 255) / 256, 256, 0, stream>>>(bcur, cap);
    k_partition<<<gp, PB, 0, stream>>>(src, dst, bcur, bucketed, cap, ne);
    k_cnt_scan<<<1, 512, 0, stream>>>(bcur, cap, cnt, csr_boff, nb);
    k_sort<<<nb, 512, 0, stream>>>(bucketed, cap, cnt, csr_boff, csr_src, node_off, dinv, n, ne, nb);
    k_dense1<<<gn, 256, 0, stream>>>(x, W1, dinv, hs1lo, hs1hi, n);
    k_agg1a<<<gn, 256, 0, stream>>>(csr_src, node_off, (const u32x4*)hs1lo, pacc, n);
    k_agg1b<<<gn, 256, 0, stream>>>(csr_src, node_off, (const u32x4*)hs1hi, pacc, b1, W2, dinv, hs2h, n);
    k_agg2<<<gn, 256, 0, stream>>>(csr_src, node_off, hs2h, b2, dinv, out, n);
}

// Round 11
// 381.668 us; speedup vs baseline: 1.1543x; 1.1543x over previous
//
#include <hip/hip_runtime.h>
#include <hip/hip_fp16.h>

#define NFEAT_IN 21
#define NHID 16
#define NOUT 6
#define BSHIFT 9
#define BW (1 << BSHIFT)     // 512 nodes per bucket
#define NB 512               // bucket array size (supports n <= 262144)
#define PB 256
#define EPT 32
#define CHUNK (PB * EPT)     // 8192 edges per partition block

typedef unsigned int u32x4 __attribute__((ext_vector_type(4)));

// static arenas: bucket b's region starts at b*cap
__global__ void k_init_bcur(int* __restrict__ bcur, int cap) {
    int b = blockIdx.x * blockDim.x + threadIdx.x;
    if (b < NB) bcur[b] = b * cap;
}

// LDS-local bucket sort per 8192-edge chunk, then COALESCED emission:
// consecutive threads write consecutive global addresses within each bucket
// run, so the wave coalescer assembles full 64B lines at issue time.
// At the 2-LDS-atomic/edge floor (~75us) — do not touch.
__global__ __launch_bounds__(256) void
k_partition(const int* __restrict__ src, const int* __restrict__ dst,
            int* __restrict__ bcur, unsigned int* __restrict__ bucketed,
            int cap, int ne) {
    __shared__ unsigned int ebd[CHUNK];     // dst value (0xFFFFFFFF = invalid)
    __shared__ unsigned short sidx[CHUNK];  // bucket-sorted pos -> chunk idx
    __shared__ int lcnt[NB], lstart[NB], lcur[NB], lbase[NB];
    __shared__ int s[PB];
    __shared__ int sh_total;
    int t = threadIdx.x;
    long base = (long)blockIdx.x * CHUNK;
    for (int b = t; b < NB; b += PB) lcnt[b] = 0;
    __syncthreads();
#pragma unroll
    for (int k = 0; k < EPT; k++) {
        int idx = t + k * PB;
        long e = base + idx;
        unsigned int v = 0xFFFFFFFFu;
        if (e < ne) {
            int d = dst[e];
            v = (unsigned int)d;
            atomicAdd(&lcnt[d >> BSHIFT], 1);
        }
        ebd[idx] = v;
    }
    __syncthreads();
    int v0 = lcnt[2 * t], v1 = lcnt[2 * t + 1];
    int pair = v0 + v1;
    s[t] = pair;
    __syncthreads();
    for (int off = 1; off < PB; off <<= 1) {
        int tv = (t >= off) ? s[t - off] : 0;
        __syncthreads();
        s[t] += tv;
        __syncthreads();
    }
    int ex = s[t] - pair;
    lstart[2 * t] = ex;          lcur[2 * t] = ex;
    lstart[2 * t + 1] = ex + v0; lcur[2 * t + 1] = ex + v0;
    if (v0 > 0) lbase[2 * t]     = atomicAdd(&bcur[2 * t],     v0);
    if (v1 > 0) lbase[2 * t + 1] = atomicAdd(&bcur[2 * t + 1], v1);
    if (t == PB - 1) sh_total = s[PB - 1];
    __syncthreads();
#pragma unroll
    for (int k = 0; k < EPT; k++) {
        int idx = t + k * PB;
        unsigned int d = ebd[idx];
        if (d != 0xFFFFFFFFu) {
            int r = atomicAdd(&lcur[d >> BSHIFT], 1);
            sidx[r] = (unsigned short)idx;
        }
    }
    __syncthreads();
    int total = sh_total;
#pragma unroll
    for (int k = 0; k < EPT; k++) {
        int j = t + k * PB;
        if (j < total) {
            int idx = sidx[j];
            unsigned int d = ebd[idx];
            int b = d >> BSHIFT;
            long gpos = (long)lbase[b] + (j - lstart[b]);
            int s_ = src[base + idx];
            if (gpos < (long)(b + 1) * cap)   // arena overflow guard (~12 sigma)
                bucketed[gpos] = ((unsigned int)s_ << BSHIFT) | (d & (BW - 1));
        }
    }
}

// counts + exclusive scan over <=512 buckets (1 block, 512 threads)
__global__ __launch_bounds__(512) void
k_cnt_scan(const int* __restrict__ bcur, int cap, int* __restrict__ cnt,
           int* __restrict__ csr_boff, int nb) {
    __shared__ int s[512];
    int t = threadIdx.x;
    int c = (t < nb) ? (bcur[t] - t * cap) : 0;
    s[t] = c;
    __syncthreads();
    for (int off = 1; off < 512; off <<= 1) {
        int tv = (t >= off) ? s[t - off] : 0;
        __syncthreads();
        s[t] += tv;
        __syncthreads();
    }
    if (t < nb) { cnt[t] = c; csr_boff[t] = s[t] - c; }
}

// Counting-sort each bucket by dst_local -> exact dst-sorted CSR.
// At the 2-LDS-atomic/edge floor — do not touch.
__global__ __launch_bounds__(512) void
k_sort(const unsigned int* __restrict__ bucketed, int cap,
       const int* __restrict__ cnt, const int* __restrict__ csr_boff,
       int* __restrict__ csr_src, int* __restrict__ node_off,
       float* __restrict__ dinv, int n, int ne, int nb) {
    __shared__ int bin[BW], sc[BW], bcur_l[BW];
    int b = blockIdx.x, t = threadIdx.x;
    bin[t] = 0;
    __syncthreads();
    size_t s0r = (size_t)b * cap;
    int c = cnt[b], s0c = csr_boff[b];
    for (int j = t; j < c; j += 512) atomicAdd(&bin[bucketed[s0r + j] & (BW - 1)], 1);
    __syncthreads();
    sc[t] = bin[t];
    __syncthreads();
    for (int off = 1; off < BW; off <<= 1) {
        int v = (t >= off) ? sc[t - off] : 0;
        __syncthreads();
        sc[t] += v;
        __syncthreads();
    }
    {
        int ex = sc[t] - bin[t];            // exclusive prefix
        bcur_l[t] = s0c + ex;
        node_off[(b << BSHIFT) + t] = s0c + ex;
        int node = (b << BSHIFT) + t;
        if (node < n) dinv[node] = rsqrtf((float)bin[t] + 1.0f);
    }
    if (b == 0 && t == 0) node_off[(size_t)nb << BSHIFT] = ne;  // sentinel
    __syncthreads();
    for (int j = t; j < c; j += 512) {
        unsigned int e = bucketed[s0r + j];
        int pos = atomicAdd(&bcur_l[e & (BW - 1)], 1);
        csr_src[pos] = (int)(e >> BSHIFT);
    }
}

// hs1h = fp16((x @ W1) * dinv[i]) — 16 halves (32B) per node
__global__ void k_dense1(const float* __restrict__ x, const float* __restrict__ W1,
                         const float* __restrict__ dinv, __half2* __restrict__ hs1h, int n) {
    __shared__ float sW[NFEAT_IN * NHID];
    for (int t = threadIdx.x; t < NFEAT_IN * NHID; t += blockDim.x) sW[t] = W1[t];
    __syncthreads();
    int i = blockIdx.x * blockDim.x + threadIdx.x;
    if (i >= n) return;
    float xi[NFEAT_IN];
#pragma unroll
    for (int k = 0; k < NFEAT_IN; k++) xi[k] = x[(size_t)i * NFEAT_IN + k];
    float di = dinv[i];
    float r[NHID];
#pragma unroll
    for (int j = 0; j < NHID; j++) {
        float acc = 0.f;
#pragma unroll
        for (int k = 0; k < NFEAT_IN; k++) acc += xi[k] * sW[k * NHID + j];
        r[j] = acc * di;
    }
    __half2* hp = hs1h + (size_t)i * 8;
#pragma unroll
    for (int q = 0; q < 8; q++) hp[q] = __floats2half2_rn(r[2 * q], r[2 * q + 1]);
}

__device__ __forceinline__ void addh16(float* acc, u32x4 u0, u32x4 u1) {
    unsigned int us[8] = {u0[0], u0[1], u0[2], u0[3], u1[0], u1[1], u1[2], u1[3]};
#pragma unroll
    for (int q = 0; q < 8; q++) {
        float2 f = __half22float2(*(const __half2*)&us[q]);
        acc[2 * q] += f.x;
        acc[2 * q + 1] += f.y;
    }
}

// CSR aggregate layer1 + relu + dense2 — 2 THREADS PER NODE.
// Round-10 finding: agg1 was latency-bound (675 cy/gather-instr) with a
// structurally small grid (1 thread/node = 12 waves/CU, 37% occ ceiling).
// Block of 256 covers 128 nodes: threads t and t+128 sweep half of node
// (base+t&127)'s edge list each; hi thread deposits its fp32 partial into
// LDS [128][17] (odd stride: conflict-free), lo thread merges + epilogue.
// 1563 blocks -> 24.4 waves/CU, 2x in-flight gathers, same traffic.
__global__ __launch_bounds__(256) void
k_agg1(const int* __restrict__ csr_src, const int* __restrict__ node_off,
       const __half2* __restrict__ hs1h, const float* __restrict__ b1,
       const float* __restrict__ W2, const float* __restrict__ dinv,
       __half2* __restrict__ hs2h, int n) {
    __shared__ float sW[NHID * NOUT];
    __shared__ float sb[NHID];
    __shared__ float lacc[128][NHID + 1];
    int t = threadIdx.x;
    if (t < NHID * NOUT) sW[t] = W2[t];
    if (t < NHID) sb[t] = b1[t];
    int tl = t & 127;
    bool lo = (t < 128);
    int i = (blockIdx.x << 7) + tl;
    bool active = (i < n);
    int beg = 0, end = 0;
    if (active) {
        int b0 = node_off[i], e0 = node_off[i + 1];
        int h = (e0 - b0 + 1) >> 1;       // lo takes ceil half
        beg = lo ? b0 : b0 + h;
        end = lo ? b0 + h : e0;
    }
    const u32x4* hb = (const u32x4*)hs1h;
    float acc[NHID];
#pragma unroll
    for (int k = 0; k < NHID; k++) acc[k] = 0.f;
    if (active && lo) {   // self contribution (self-loop: A+I)
        u32x4 u0 = hb[(size_t)i * 2], u1 = hb[(size_t)i * 2 + 1];
        unsigned int us[8] = {u0[0], u0[1], u0[2], u0[3], u1[0], u1[1], u1[2], u1[3]};
#pragma unroll
        for (int q = 0; q < 8; q++) {
            float2 f = __half22float2(*(const __half2*)&us[q]);
            acc[2 * q] = f.x;
            acc[2 * q + 1] = f.y;
        }
    }
    int j = beg;
    for (; j + 4 <= end; j += 4) {
        int s0_ = csr_src[j], s1_ = csr_src[j + 1];
        int s2_ = csr_src[j + 2], s3_ = csr_src[j + 3];
        u32x4 a0 = hb[(size_t)s0_ * 2], a1 = hb[(size_t)s0_ * 2 + 1];
        u32x4 b0 = hb[(size_t)s1_ * 2], b1v = hb[(size_t)s1_ * 2 + 1];
        u32x4 c0 = hb[(size_t)s2_ * 2], c1 = hb[(size_t)s2_ * 2 + 1];
        u32x4 d0 = hb[(size_t)s3_ * 2], d1 = hb[(size_t)s3_ * 2 + 1];
        addh16(acc, a0, a1);
        addh16(acc, b0, b1v);
        addh16(acc, c0, c1);
        addh16(acc, d0, d1);
    }
    for (; j < end; j++) {
        int s_ = csr_src[j];
        addh16(acc, hb[(size_t)s_ * 2], hb[(size_t)s_ * 2 + 1]);
    }
    if (!lo) {
#pragma unroll
        for (int k = 0; k < NHID; k++) lacc[tl][k] = acc[k];
    }
    __syncthreads();
    if (!lo || !active) return;
#pragma unroll
    for (int k = 0; k < NHID; k++) acc[k] += lacc[tl][k];
    float di = dinv[i];
    float z[NHID];
#pragma unroll
    for (int k = 0; k < NHID; k++) z[k] = fmaxf(acc[k] * di + sb[k], 0.0f);
    float h[8];
#pragma unroll
    for (int kk = 0; kk < NOUT; kk++) {
        float s = 0.f;
#pragma unroll
        for (int jj = 0; jj < NHID; jj++) s += z[jj] * sW[jj * NOUT + kk];
        h[kk] = s * di;
    }
    h[6] = 0.f; h[7] = 0.f;
    __half2* op = hs2h + (size_t)i * 4;
#pragma unroll
    for (int q = 0; q < 4; q++) op[q] = __floats2half2_rn(h[2 * q], h[2 * q + 1]);
}

// CSR aggregate layer2 + bias + log_softmax. One thread per dst node.
// (round-7 form, plain loads)
__global__ __launch_bounds__(256) void
k_agg2(const int* __restrict__ csr_src, const int* __restrict__ node_off,
       const __half2* __restrict__ hs2h, const float* __restrict__ b2,
       const float* __restrict__ dinv, float* __restrict__ out, int n) {
    __shared__ float sb[NOUT];
    int t = threadIdx.x;
    if (t < NOUT) sb[t] = b2[t];
    __syncthreads();
    int i = blockIdx.x * blockDim.x + t;
    if (i >= n) return;
    int beg = node_off[i], end = node_off[i + 1];
    const u32x4* hb = (const u32x4*)hs2h;
    float acc[NOUT];
    {   // self
        u32x4 u = hb[(size_t)i];
        unsigned int us[3] = {u[0], u[1], u[2]};
#pragma unroll
        for (int q = 0; q < 3; q++) {
            float2 f = __half22float2(*(const __half2*)&us[q]);
            acc[2 * q] = f.x;
            acc[2 * q + 1] = f.y;
        }
    }
    int j = beg;
    for (; j + 8 <= end; j += 8) {
        int sid[8];
#pragma unroll
        for (int q = 0; q < 8; q++) sid[q] = csr_src[j + q];
        u32x4 u[8];
#pragma unroll
        for (int q = 0; q < 8; q++) u[q] = hb[(size_t)sid[q]];
#pragma unroll
        for (int q = 0; q < 8; q++) {
            unsigned int us[3] = {u[q][0], u[q][1], u[q][2]};
#pragma unroll
            for (int w = 0; w < 3; w++) {
                float2 fv = __half22float2(*(const __half2*)&us[w]);
                acc[2 * w] += fv.x;
                acc[2 * w + 1] += fv.y;
            }
        }
    }
    for (; j < end; j++) {
        u32x4 u = hb[(size_t)csr_src[j]];
        unsigned int us[3] = {u[0], u[1], u[2]};
#pragma unroll
        for (int w = 0; w < 3; w++) {
            float2 fv = __half22float2(*(const __half2*)&us[w]);
            acc[2 * w] += fv.x;
            acc[2 * w + 1] += fv.y;
        }
    }
    float di = dinv[i];
    float v[NOUT];
#pragma unroll
    for (int k = 0; k < NOUT; k++) v[k] = acc[k] * di + sb[k];
    float m = -1e30f;
#pragma unroll
    for (int k = 0; k < NOUT; k++) m = fmaxf(m, v[k]);
    float se = 0.f;
#pragma unroll
    for (int k = 0; k < NOUT; k++) se += expf(v[k] - m);
    float l = logf(se);
#pragma unroll
    for (int k = 0; k < NOUT; k++) out[(size_t)i * NOUT + k] = v[k] - m - l;
}

extern "C" void kernel_launch(void* const* d_in, const int* in_sizes, int n_in,
                              void* d_out, int out_size, void* d_ws, size_t ws_size,
                              hipStream_t stream) {
    const float* x  = (const float*)d_in[0];
    const int*   ei = (const int*)d_in[1];
    const float* W1 = (const float*)d_in[2];
    const float* b1 = (const float*)d_in[3];
    const float* W2 = (const float*)d_in[4];
    const float* b2 = (const float*)d_in[5];
    float* out = (float*)d_out;

    int n  = in_sizes[0] / NFEAT_IN;   // 200000
    int ne = in_sizes[1] / 2;          // 6400000
    const int* src = ei;
    const int* dst = ei + ne;

    int nb = (n + BW - 1) >> BSHIFT;          // 391
    // arena capacity per bucket: mean + ~12 sigma headroom for uniform dst
    int cap = (ne + nb - 1) / nb + ne / (nb * 16) + 1536;

    char* base = (char*)d_ws;
    size_t off = 0;
    auto alloc = [&](size_t bytes) {
        void* p = base + off;
        off += (bytes + 63) & ~(size_t)63;
        return p;
    };
    int* bcur     = (int*)alloc(NB * 4);
    int* cnt      = (int*)alloc(NB * 4);
    int* csr_boff = (int*)alloc(NB * 4);
    unsigned int* bucketed = (unsigned int*)alloc((size_t)nb * cap * 4);
    int* csr_src  = (int*)alloc((size_t)ne * 4);
    int* node_off = (int*)alloc(((size_t)nb * BW + 1) * 4);
    float* dinv   = (float*)alloc((size_t)n * 4);
    // hs1h/hs2h overlay the arena (dead after k_sort; hs* written after)
    __half2* hs1h;
    __half2* hs2h;
    if ((size_t)nb * cap * 4 >= (size_t)n * 48) {
        hs1h = (__half2*)bucketed;
        hs2h = (__half2*)((char*)bucketed + (size_t)n * 32);
    } else {
        hs1h = (__half2*)alloc((size_t)n * 32);
        hs2h = (__half2*)alloc((size_t)n * 16);
    }

    int gp  = (ne + CHUNK - 1) / CHUNK;       // 782
    int gn  = (n + 255) / 256;
    int gn1 = (n + 127) / 128;                // 2 threads/node for k_agg1

    k_init_bcur<<<(NB + 255) / 256, 256, 0, stream>>>(bcur, cap);
    k_partition<<<gp, PB, 0, stream>>>(src, dst, bcur, bucketed, cap, ne);
    k_cnt_scan<<<1, 512, 0, stream>>>(bcur, cap, cnt, csr_boff, nb);
    k_sort<<<nb, 512, 0, stream>>>(bucketed, cap, cnt, csr_boff, csr_src, node_off, dinv, n, ne, nb);
    k_dense1<<<gn, 256, 0, stream>>>(x, W1, dinv, hs1h, n);
    k_agg1<<<gn1, 256, 0, stream>>>(csr_src, node_off, hs1h, b1, W2, dinv, hs2h, n);
    k_agg2<<<gn, 256, 0, stream>>>(csr_src, node_off, hs2h, b2, dinv, out, n);
}

// Round 12
// 366.929 us; speedup vs baseline: 1.2007x; 1.0402x over previous
//
#include <hip/hip_runtime.h>
#include <hip/hip_fp16.h>

#define NFEAT_IN 21
#define NHID 16
#define NOUT 6
#define BSHIFT 9
#define BW (1 << BSHIFT)     // 512 nodes per bucket
#define NB 512               // bucket array size (supports n <= 262144)
#define PB 256
#define EPT 32
#define CHUNK (PB * EPT)     // 8192 edges per partition block

typedef unsigned int u32x4 __attribute__((ext_vector_type(4)));

// static arenas: bucket b's region starts at b*cap
__global__ void k_init_bcur(int* __restrict__ bcur, int cap) {
    int b = blockIdx.x * blockDim.x + threadIdx.x;
    if (b < NB) bcur[b] = b * cap;
}

// LDS-local bucket sort per 8192-edge chunk, then COALESCED emission.
// At the 2-LDS-atomic/edge floor (~80us) — do not touch.
__global__ __launch_bounds__(256) void
k_partition(const int* __restrict__ src, const int* __restrict__ dst,
            int* __restrict__ bcur, unsigned int* __restrict__ bucketed,
            int cap, int ne) {
    __shared__ unsigned int ebd[CHUNK];     // dst value (0xFFFFFFFF = invalid)
    __shared__ unsigned short sidx[CHUNK];  // bucket-sorted pos -> chunk idx
    __shared__ int lcnt[NB], lstart[NB], lcur[NB], lbase[NB];
    __shared__ int s[PB];
    __shared__ int sh_total;
    int t = threadIdx.x;
    long base = (long)blockIdx.x * CHUNK;
    for (int b = t; b < NB; b += PB) lcnt[b] = 0;
    __syncthreads();
#pragma unroll
    for (int k = 0; k < EPT; k++) {
        int idx = t + k * PB;
        long e = base + idx;
        unsigned int v = 0xFFFFFFFFu;
        if (e < ne) {
            int d = dst[e];
            v = (unsigned int)d;
            atomicAdd(&lcnt[d >> BSHIFT], 1);
        }
        ebd[idx] = v;
    }
    __syncthreads();
    int v0 = lcnt[2 * t], v1 = lcnt[2 * t + 1];
    int pair = v0 + v1;
    s[t] = pair;
    __syncthreads();
    for (int off = 1; off < PB; off <<= 1) {
        int tv = (t >= off) ? s[t - off] : 0;
        __syncthreads();
        s[t] += tv;
        __syncthreads();
    }
    int ex = s[t] - pair;
    lstart[2 * t] = ex;          lcur[2 * t] = ex;
    lstart[2 * t + 1] = ex + v0; lcur[2 * t + 1] = ex + v0;
    if (v0 > 0) lbase[2 * t]     = atomicAdd(&bcur[2 * t],     v0);
    if (v1 > 0) lbase[2 * t + 1] = atomicAdd(&bcur[2 * t + 1], v1);
    if (t == PB - 1) sh_total = s[PB - 1];
    __syncthreads();
#pragma unroll
    for (int k = 0; k < EPT; k++) {
        int idx = t + k * PB;
        unsigned int d = ebd[idx];
        if (d != 0xFFFFFFFFu) {
            int r = atomicAdd(&lcur[d >> BSHIFT], 1);
            sidx[r] = (unsigned short)idx;
        }
    }
    __syncthreads();
    int total = sh_total;
#pragma unroll
    for (int k = 0; k < EPT; k++) {
        int j = t + k * PB;
        if (j < total) {
            int idx = sidx[j];
            unsigned int d = ebd[idx];
            int b = d >> BSHIFT;
            long gpos = (long)lbase[b] + (j - lstart[b]);
            int s_ = src[base + idx];
            if (gpos < (long)(b + 1) * cap)   // arena overflow guard (~12 sigma)
                bucketed[gpos] = ((unsigned int)s_ << BSHIFT) | (d & (BW - 1));
        }
    }
}

// counts + exclusive scan over <=512 buckets (1 block, 512 threads)
__global__ __launch_bounds__(512) void
k_cnt_scan(const int* __restrict__ bcur, int cap, int* __restrict__ cnt,
           int* __restrict__ csr_boff, int nb) {
    __shared__ int s[512];
    int t = threadIdx.x;
    int c = (t < nb) ? (bcur[t] - t * cap) : 0;
    s[t] = c;
    __syncthreads();
    for (int off = 1; off < 512; off <<= 1) {
        int tv = (t >= off) ? s[t - off] : 0;
        __syncthreads();
        s[t] += tv;
        __syncthreads();
    }
    if (t < nb) { cnt[t] = c; csr_boff[t] = s[t] - c; }
}

// Counting-sort each bucket by dst_local -> exact dst-sorted CSR.
// At the 2-LDS-atomic/edge floor — do not touch.
__global__ __launch_bounds__(512) void
k_sort(const unsigned int* __restrict__ bucketed, int cap,
       const int* __restrict__ cnt, const int* __restrict__ csr_boff,
       int* __restrict__ csr_src, int* __restrict__ node_off,
       float* __restrict__ dinv, int n, int ne, int nb) {
    __shared__ int bin[BW], sc[BW], bcur_l[BW];
    int b = blockIdx.x, t = threadIdx.x;
    bin[t] = 0;
    __syncthreads();
    size_t s0r = (size_t)b * cap;
    int c = cnt[b], s0c = csr_boff[b];
    for (int j = t; j < c; j += 512) atomicAdd(&bin[bucketed[s0r + j] & (BW - 1)], 1);
    __syncthreads();
    sc[t] = bin[t];
    __syncthreads();
    for (int off = 1; off < BW; off <<= 1) {
        int v = (t >= off) ? sc[t - off] : 0;
        __syncthreads();
        sc[t] += v;
        __syncthreads();
    }
    {
        int ex = sc[t] - bin[t];            // exclusive prefix
        bcur_l[t] = s0c + ex;
        node_off[(b << BSHIFT) + t] = s0c + ex;
        int node = (b << BSHIFT) + t;
        if (node < n) dinv[node] = rsqrtf((float)bin[t] + 1.0f);
    }
    if (b == 0 && t == 0) node_off[(size_t)nb << BSHIFT] = ne;  // sentinel
    __syncthreads();
    for (int j = t; j < c; j += 512) {
        unsigned int e = bucketed[s0r + j];
        int pos = atomicAdd(&bcur_l[e & (BW - 1)], 1);
        csr_src[pos] = (int)(e >> BSHIFT);
    }
}

// hs1h = fp16((x @ W1) * dinv[i]) — 16 halves (32B) per node
__global__ void k_dense1(const float* __restrict__ x, const float* __restrict__ W1,
                         const float* __restrict__ dinv, __half2* __restrict__ hs1h, int n) {
    __shared__ float sW[NFEAT_IN * NHID];
    for (int t = threadIdx.x; t < NFEAT_IN * NHID; t += blockDim.x) sW[t] = W1[t];
    __syncthreads();
    int i = blockIdx.x * blockDim.x + threadIdx.x;
    if (i >= n) return;
    float xi[NFEAT_IN];
#pragma unroll
    for (int k = 0; k < NFEAT_IN; k++) xi[k] = x[(size_t)i * NFEAT_IN + k];
    float di = dinv[i];
    float r[NHID];
#pragma unroll
    for (int j = 0; j < NHID; j++) {
        float acc = 0.f;
#pragma unroll
        for (int k = 0; k < NFEAT_IN; k++) acc += xi[k] * sW[k * NHID + j];
        r[j] = acc * di;
    }
    __half2* hp = hs1h + (size_t)i * 8;
#pragma unroll
    for (int q = 0; q < 8; q++) hp[q] = __floats2half2_rn(r[2 * q], r[2 * q + 1]);
}

__device__ __forceinline__ void addh16(float* acc, u32x4 u0, u32x4 u1) {
    unsigned int us[8] = {u0[0], u0[1], u0[2], u0[3], u1[0], u1[1], u1[2], u1[3]};
#pragma unroll
    for (int q = 0; q < 8; q++) {
        float2 f = __half22float2(*(const __half2*)&us[q]);
        acc[2 * q] += f.x;
        acc[2 * q + 1] += f.y;
    }
}

// CSR aggregate layer1 + relu + dense2 — 4 THREADS PER NODE.
// Round-11 finding: 2 threads/node took agg1 110->91us, occ 24->40%, gather
// 2.6->3.1 TB/s — latency/concurrency bound confirmed, wave headroom remains.
// Block of 256 covers 64 nodes; segments seg=0..3 sweep quarter edge-lists;
// segs 1-3 deposit fp32 partials into lacc[3][64][17] (odd stride), seg 0
// merges + epilogue. 3125 blocks -> 12.2 blocks/CU (LDS 13.3KB allows it).
__global__ __launch_bounds__(256) void
k_agg1(const int* __restrict__ csr_src, const int* __restrict__ node_off,
       const __half2* __restrict__ hs1h, const float* __restrict__ b1,
       const float* __restrict__ W2, const float* __restrict__ dinv,
       __half2* __restrict__ hs2h, int n) {
    __shared__ float sW[NHID * NOUT];
    __shared__ float sb[NHID];
    __shared__ float lacc[3][64][NHID + 1];
    int t = threadIdx.x;
    if (t < NHID * NOUT) sW[t] = W2[t];
    if (t < NHID) sb[t] = b1[t];
    int tl = t & 63;
    int seg = t >> 6;            // 0..3
    int i = (blockIdx.x << 6) + tl;
    bool active = (i < n);
    int beg = 0, end = 0;
    if (active) {
        int b0 = node_off[i], e0 = node_off[i + 1];
        int len = e0 - b0;
        beg = b0 + (len * seg) / 4;
        end = b0 + (len * (seg + 1)) / 4;
    }
    const u32x4* hb = (const u32x4*)hs1h;
    float acc[NHID];
#pragma unroll
    for (int k = 0; k < NHID; k++) acc[k] = 0.f;
    if (active && seg == 0) {   // self contribution (self-loop: A+I)
        u32x4 u0 = hb[(size_t)i * 2], u1 = hb[(size_t)i * 2 + 1];
        unsigned int us[8] = {u0[0], u0[1], u0[2], u0[3], u1[0], u1[1], u1[2], u1[3]};
#pragma unroll
        for (int q = 0; q < 8; q++) {
            float2 f = __half22float2(*(const __half2*)&us[q]);
            acc[2 * q] = f.x;
            acc[2 * q + 1] = f.y;
        }
    }
    int j = beg;
    for (; j + 4 <= end; j += 4) {
        int s0_ = csr_src[j], s1_ = csr_src[j + 1];
        int s2_ = csr_src[j + 2], s3_ = csr_src[j + 3];
        u32x4 a0 = hb[(size_t)s0_ * 2], a1 = hb[(size_t)s0_ * 2 + 1];
        u32x4 b0 = hb[(size_t)s1_ * 2], b1v = hb[(size_t)s1_ * 2 + 1];
        u32x4 c0 = hb[(size_t)s2_ * 2], c1 = hb[(size_t)s2_ * 2 + 1];
        u32x4 d0 = hb[(size_t)s3_ * 2], d1 = hb[(size_t)s3_ * 2 + 1];
        addh16(acc, a0, a1);
        addh16(acc, b0, b1v);
        addh16(acc, c0, c1);
        addh16(acc, d0, d1);
    }
    for (; j < end; j++) {
        int s_ = csr_src[j];
        addh16(acc, hb[(size_t)s_ * 2], hb[(size_t)s_ * 2 + 1]);
    }
    if (seg != 0) {
#pragma unroll
        for (int k = 0; k < NHID; k++) lacc[seg - 1][tl][k] = acc[k];
    }
    __syncthreads();
    if (seg != 0 || !active) return;
#pragma unroll
    for (int k = 0; k < NHID; k++)
        acc[k] += lacc[0][tl][k] + lacc[1][tl][k] + lacc[2][tl][k];
    float di = dinv[i];
    float z[NHID];
#pragma unroll
    for (int k = 0; k < NHID; k++) z[k] = fmaxf(acc[k] * di + sb[k], 0.0f);
    float h[8];
#pragma unroll
    for (int kk = 0; kk < NOUT; kk++) {
        float s = 0.f;
#pragma unroll
        for (int jj = 0; jj < NHID; jj++) s += z[jj] * sW[jj * NOUT + kk];
        h[kk] = s * di;
    }
    h[6] = 0.f; h[7] = 0.f;
    __half2* op = hs2h + (size_t)i * 4;
#pragma unroll
    for (int q = 0; q < 4; q++) op[q] = __floats2half2_rn(h[2 * q], h[2 * q + 1]);
}

// CSR aggregate layer2 + bias + log_softmax — 2 THREADS PER NODE
// (same cure as agg1: 1 thread/node was 12 waves/CU, latency-bound).
__global__ __launch_bounds__(256) void
k_agg2(const int* __restrict__ csr_src, const int* __restrict__ node_off,
       const __half2* __restrict__ hs2h, const float* __restrict__ b2,
       const float* __restrict__ dinv, float* __restrict__ out, int n) {
    __shared__ float sb[NOUT];
    __shared__ float lacc[128][NOUT + 1];
    int t = threadIdx.x;
    if (t < NOUT) sb[t] = b2[t];
    int tl = t & 127;
    bool lo = (t < 128);
    int i = (blockIdx.x << 7) + tl;
    bool active = (i < n);
    int beg = 0, end = 0;
    if (active) {
        int b0 = node_off[i], e0 = node_off[i + 1];
        int h = (e0 - b0 + 1) >> 1;
        beg = lo ? b0 : b0 + h;
        end = lo ? b0 + h : e0;
    }
    const u32x4* hb = (const u32x4*)hs2h;
    float acc[NOUT];
#pragma unroll
    for (int k = 0; k < NOUT; k++) acc[k] = 0.f;
    if (active && lo) {   // self
        u32x4 u = hb[(size_t)i];
        unsigned int us[3] = {u[0], u[1], u[2]};
#pragma unroll
        for (int q = 0; q < 3; q++) {
            float2 f = __half22float2(*(const __half2*)&us[q]);
            acc[2 * q] = f.x;
            acc[2 * q + 1] = f.y;
        }
    }
    int j = beg;
    for (; j + 8 <= end; j += 8) {
        int sid[8];
#pragma unroll
        for (int q = 0; q < 8; q++) sid[q] = csr_src[j + q];
        u32x4 u[8];
#pragma unroll
        for (int q = 0; q < 8; q++) u[q] = hb[(size_t)sid[q]];
#pragma unroll
        for (int q = 0; q < 8; q++) {
            unsigned int us[3] = {u[q][0], u[q][1], u[q][2]};
#pragma unroll
            for (int w = 0; w < 3; w++) {
                float2 fv = __half22float2(*(const __half2*)&us[w]);
                acc[2 * w] += fv.x;
                acc[2 * w + 1] += fv.y;
            }
        }
    }
    for (; j < end; j++) {
        u32x4 u = hb[(size_t)csr_src[j]];
        unsigned int us[3] = {u[0], u[1], u[2]};
#pragma unroll
        for (int w = 0; w < 3; w++) {
            float2 fv = __half22float2(*(const __half2*)&us[w]);
            acc[2 * w] += fv.x;
            acc[2 * w + 1] += fv.y;
        }
    }
    if (!lo) {
#pragma unroll
        for (int k = 0; k < NOUT; k++) lacc[tl][k] = acc[k];
    }
    __syncthreads();
    if (!lo || !active) return;
#pragma unroll
    for (int k = 0; k < NOUT; k++) acc[k] += lacc[tl][k];
    float di = dinv[i];
    float v[NOUT];
#pragma unroll
    for (int k = 0; k < NOUT; k++) v[k] = acc[k] * di + sb[k];
    float m = -1e30f;
#pragma unroll
    for (int k = 0; k < NOUT; k++) m = fmaxf(m, v[k]);
    float se = 0.f;
#pragma unroll
    for (int k = 0; k < NOUT; k++) se += expf(v[k] - m);
    float l = logf(se);
#pragma unroll
    for (int k = 0; k < NOUT; k++) out[(size_t)i * NOUT + k] = v[k] - m - l;
}

extern "C" void kernel_launch(void* const* d_in, const int* in_sizes, int n_in,
                              void* d_out, int out_size, void* d_ws, size_t ws_size,
                              hipStream_t stream) {
    const float* x  = (const float*)d_in[0];
    const int*   ei = (const int*)d_in[1];
    const float* W1 = (const float*)d_in[2];
    const float* b1 = (const float*)d_in[3];
    const float* W2 = (const float*)d_in[4];
    const float* b2 = (const float*)d_in[5];
    float* out = (float*)d_out;

    int n  = in_sizes[0] / NFEAT_IN;   // 200000
    int ne = in_sizes[1] / 2;          // 6400000
    const int* src = ei;
    const int* dst = ei + ne;

    int nb = (n + BW - 1) >> BSHIFT;          // 391
    // arena capacity per bucket: mean + ~12 sigma headroom for uniform dst
    int cap = (ne + nb - 1) / nb + ne / (nb * 16) + 1536;

    char* base = (char*)d_ws;
    size_t off = 0;
    auto alloc = [&](size_t bytes) {
        void* p = base + off;
        off += (bytes + 63) & ~(size_t)63;
        return p;
    };
    int* bcur     = (int*)alloc(NB * 4);
    int* cnt      = (int*)alloc(NB * 4);
    int* csr_boff = (int*)alloc(NB * 4);
    unsigned int* bucketed = (unsigned int*)alloc((size_t)nb * cap * 4);
    int* csr_src  = (int*)alloc((size_t)ne * 4);
    int* node_off = (int*)alloc(((size_t)nb * BW + 1) * 4);
    float* dinv   = (float*)alloc((size_t)n * 4);
    // hs1h/hs2h overlay the arena (dead after k_sort; hs* written after)
    __half2* hs1h;
    __half2* hs2h;
    if ((size_t)nb * cap * 4 >= (size_t)n * 48) {
        hs1h = (__half2*)bucketed;
        hs2h = (__half2*)((char*)bucketed + (size_t)n * 32);
    } else {
        hs1h = (__half2*)alloc((size_t)n * 32);
        hs2h = (__half2*)alloc((size_t)n * 16);
    }

    int gp  = (ne + CHUNK - 1) / CHUNK;       // 782
    int gn  = (n + 255) / 256;
    int gn1 = (n + 63) / 64;                  // 4 threads/node for k_agg1
    int gn2 = (n + 127) / 128;                // 2 threads/node for k_agg2

    k_init_bcur<<<(NB + 255) / 256, 256, 0, stream>>>(bcur, cap);
    k_partition<<<gp, PB, 0, stream>>>(src, dst, bcur, bucketed, cap, ne);
    k_cnt_scan<<<1, 512, 0, stream>>>(bcur, cap, cnt, csr_boff, nb);
    k_sort<<<nb, 512, 0, stream>>>(bucketed, cap, cnt, csr_boff, csr_src, node_off, dinv, n, ne, nb);
    k_dense1<<<gn, 256, 0, stream>>>(x, W1, dinv, hs1h, n);
    k_agg1<<<gn1, 256, 0, stream>>>(csr_src, node_off, hs1h, b1, W2, dinv, hs2h, n);
    k_agg2<<<gn2, 256, 0, stream>>>(csr_src, node_off, hs2h, b2, dinv, out, n);
}